// Round 3
// baseline (247.172 us; speedup 1.0000x reference)
//
#include <hip/hip_runtime.h>

typedef __attribute__((ext_vector_type(4))) float f32x4;
typedef __attribute__((ext_vector_type(8))) short bf16x8;

__device__ __forceinline__ unsigned short f2bf(float f) {
  unsigned int u = __builtin_bit_cast(unsigned int, f);
  u += 0x7FFFu + ((u >> 16) & 1u);   // RTNE
  return (unsigned short)(u >> 16);
}

// ---- K0a: P[b][h] = b_attn[h] + dot(W_attn[h, 0:512], hidden[b, :])
__global__ __launch_bounds__(256) void k_prep_p(
    const float* __restrict__ hidden, const float* __restrict__ W,
    const float* __restrict__ bias, float* __restrict__ P) {
  __shared__ float hsh[512];
  const int b = blockIdx.x;
  for (int i = threadIdx.x; i < 512; i += 256) hsh[i] = hidden[b * 512 + i];
  __syncthreads();
  for (int h = threadIdx.x; h < 512; h += 256) {
    const float* wr = W + (long)h * 1536;
    float s = 0.f;
#pragma unroll 4
    for (int f = 0; f < 512; f += 4) {
      float4 wv = *reinterpret_cast<const float4*>(wr + f);
      s += wv.x * hsh[f] + wv.y * hsh[f + 1] + wv.z * hsh[f + 2] + wv.w * hsh[f + 3];
    }
    P[b * 512 + h] = bias[h] + s;
  }
}

// ---- K0b: W2t[kb][h][kk] = bf16(W_attn[h][512 + kb*64 + kk]), kb<16, h<512, kk<64
__global__ __launch_bounds__(256) void k_prep_w(
    const float* __restrict__ W, unsigned short* __restrict__ W2t) {
  const int id = blockIdx.x * 256 + threadIdx.x;  // 65536 threads, 8 elems each
  const int kk8 = (id & 7) * 8;
  const int h = (id >> 3) & 511;
  const int kb = id >> 12;
  const float* src = W + (long)h * 1536 + 512 + kb * 64 + kk8;
  float4 a = *reinterpret_cast<const float4*>(src);
  float4 c = *reinterpret_cast<const float4*>(src + 4);
  union { unsigned short u[8]; bf16x8 v; } o;
  o.u[0] = f2bf(a.x); o.u[1] = f2bf(a.y); o.u[2] = f2bf(a.z); o.u[3] = f2bf(a.w);
  o.u[4] = f2bf(c.x); o.u[5] = f2bf(c.y); o.u[6] = f2bf(c.z); o.u[7] = f2bf(c.w);
  *reinterpret_cast<bf16x8*>(W2t + (long)kb * 32768 + h * 64 + kk8) = o.v;
}

// ---- K1: fused GEMM + tanh + v-reduce -> logits partials
// grid 1024 = 512 mtiles x 2 ntiles; 512 threads = 8 waves (2M x 4N), wave tile 64x64
// BM=128 BN=256 BK=64. Each ntile writes its PARTIAL h-sum to its own buffer;
// k_softmax sums the two partials (fixes the round-2 overwrite bug).
__global__ __launch_bounds__(512, 2) void k_main(
    const float* __restrict__ enc, const short* __restrict__ W2t,
    const float* __restrict__ P, const float* __restrict__ v,
    float* __restrict__ logits_part) {
  __shared__ short As[2][128 * 64];     // 2 x 16 KB, [row][slot^(row&7)] 16B slots
  __shared__ float attred[128][4];

  const int tid = threadIdx.x;
  const int lane = tid & 63;
  const int w = tid >> 6;
  const int wr = w >> 2, wc = w & 3;
  const int hl = lane & 15, kg = lane >> 4;

  // XCD swizzle: the two ntiles of one mtile land 8 apart -> same XCD slot stream
  const int bid = blockIdx.x;
  const int l = (bid & 7) * 128 + (bid >> 3);
  const int mtile = l >> 1, ntile = l & 1;
  const long rowbase = (long)mtile * 128;
  const int colbase = ntile * 256;
  const int b = (int)(rowbase >> 12);   // 128 | 4096, same batch for whole block

  // staging: thread t -> row r=t>>2, k-group g=t&3 (16 floats at k=g*16)
  const int st_r = tid >> 2;
  const int st_g = tid & 3;
  const float4* gs4 =
      reinterpret_cast<const float4*>(enc + (rowbase + st_r) * 1024 + st_g * 16);
  const int wi0 = st_r * 64 + (((st_g * 2) ^ (st_r & 7)) * 8);
  const int wi1 = st_r * 64 + ((((st_g * 2) | 1) ^ (st_r & 7)) * 8);

  // A-frag read: row R = wr*64 + mi*16 + hl, logical slot = ks*4+kg, R&7 == hl&7
  const int abase = (wr * 64 + hl) * 64;
  const int aoff0 = ((kg) ^ (hl & 7)) * 8;
  const int aoff1 = ((4 + kg) ^ (hl & 7)) * 8;

  // B-frag: h = colbase + wc*64 + ni*16 + hl; elem = kb*32768 + h*64 + ks*32 + kg*8
  const short* bptr = W2t + (colbase + wc * 64 + hl) * 64 + kg * 8;

  f32x4 acc[4][4];
#pragma unroll
  for (int mi = 0; mi < 4; ++mi)
#pragma unroll
    for (int ni = 0; ni < 4; ++ni) acc[mi][ni] = (f32x4){0.f, 0.f, 0.f, 0.f};

  float4 st0 = gs4[0], st1 = gs4[1], st2 = gs4[2], st3 = gs4[3];
  {
    union { unsigned short u[8]; bf16x8 v; } o0, o1;
    o0.u[0]=f2bf(st0.x); o0.u[1]=f2bf(st0.y); o0.u[2]=f2bf(st0.z); o0.u[3]=f2bf(st0.w);
    o0.u[4]=f2bf(st1.x); o0.u[5]=f2bf(st1.y); o0.u[6]=f2bf(st1.z); o0.u[7]=f2bf(st1.w);
    o1.u[0]=f2bf(st2.x); o1.u[1]=f2bf(st2.y); o1.u[2]=f2bf(st2.z); o1.u[3]=f2bf(st2.w);
    o1.u[4]=f2bf(st3.x); o1.u[5]=f2bf(st3.y); o1.u[6]=f2bf(st3.z); o1.u[7]=f2bf(st3.w);
    *reinterpret_cast<bf16x8*>(&As[0][wi0]) = o0.v;
    *reinterpret_cast<bf16x8*>(&As[0][wi1]) = o1.v;
  }
  __syncthreads();

  int cur = 0;
  for (int kb = 0; kb < 16; ++kb) {
    if (kb < 15) {  // issue next enc tile loads early (hide HBM under this iter)
      st0 = gs4[(kb + 1) * 16 + 0];
      st1 = gs4[(kb + 1) * 16 + 1];
      st2 = gs4[(kb + 1) * 16 + 2];
      st3 = gs4[(kb + 1) * 16 + 3];
    }
    const short* bkb = bptr + kb * 32768;
    bf16x8 bf[2][4];
#pragma unroll
    for (int ks = 0; ks < 2; ++ks)
#pragma unroll
      for (int ni = 0; ni < 4; ++ni)
        bf[ks][ni] = *reinterpret_cast<const bf16x8*>(bkb + ni * 1024 + ks * 32);

#pragma unroll
    for (int ks = 0; ks < 2; ++ks) {
      bf16x8 af[4];
      const int ao = ks ? aoff1 : aoff0;
#pragma unroll
      for (int mi = 0; mi < 4; ++mi)
        af[mi] = *reinterpret_cast<const bf16x8*>(&As[cur][abase + mi * 1024 + ao]);
#pragma unroll
      for (int mi = 0; mi < 4; ++mi)
#pragma unroll
        for (int ni = 0; ni < 4; ++ni)
          acc[mi][ni] = __builtin_amdgcn_mfma_f32_16x16x32_bf16(af[mi], bf[ks][ni],
                                                                acc[mi][ni], 0, 0, 0);
    }

    if (kb < 15) {  // convert + write next tile into the other buffer
      union { unsigned short u[8]; bf16x8 v; } o0, o1;
      o0.u[0]=f2bf(st0.x); o0.u[1]=f2bf(st0.y); o0.u[2]=f2bf(st0.z); o0.u[3]=f2bf(st0.w);
      o0.u[4]=f2bf(st1.x); o0.u[5]=f2bf(st1.y); o0.u[6]=f2bf(st1.z); o0.u[7]=f2bf(st1.w);
      o1.u[0]=f2bf(st2.x); o1.u[1]=f2bf(st2.y); o1.u[2]=f2bf(st2.z); o1.u[3]=f2bf(st2.w);
      o1.u[4]=f2bf(st3.x); o1.u[5]=f2bf(st3.y); o1.u[6]=f2bf(st3.z); o1.u[7]=f2bf(st3.w);
      const int bo = (cur ^ 1) * (128 * 64);
      *reinterpret_cast<bf16x8*>(&As[0][bo + wi0]) = o0.v;
      *reinterpret_cast<bf16x8*>(&As[0][bo + wi1]) = o1.v;
    }
    __syncthreads();
    cur ^= 1;
  }

  // epilogue: x = acc + P[b][h]; part += v[h]*tanh(x); reduce over hl, then wc
  float part[4][4];
#pragma unroll
  for (int mi = 0; mi < 4; ++mi)
#pragma unroll
    for (int r = 0; r < 4; ++r) part[mi][r] = 0.f;

#pragma unroll
  for (int ni = 0; ni < 4; ++ni) {
    const int h = colbase + wc * 64 + ni * 16 + hl;
    const float ph = P[b * 512 + h];
    const float vh = v[h];
#pragma unroll
    for (int mi = 0; mi < 4; ++mi)
#pragma unroll
      for (int r = 0; r < 4; ++r) {
        float x = acc[mi][ni][r] + ph;
        float e = __expf(2.f * x);
        part[mi][r] += vh * (1.f - 2.f * __frcp_rn(e + 1.f));
      }
  }
#pragma unroll
  for (int off = 1; off < 16; off <<= 1)
#pragma unroll
    for (int mi = 0; mi < 4; ++mi)
#pragma unroll
      for (int r = 0; r < 4; ++r)
        part[mi][r] += __shfl_xor(part[mi][r], off, 16);

  if (hl == 0) {
#pragma unroll
    for (int mi = 0; mi < 4; ++mi)
#pragma unroll
      for (int r = 0; r < 4; ++r)
        attred[wr * 64 + mi * 16 + kg * 4 + r][wc] = part[mi][r];
  }
  __syncthreads();
  if (tid < 128)
    logits_part[ntile * 65536 + rowbase + tid] =
        attred[tid][0] + attred[tid][1] + attred[tid][2] + attred[tid][3];
}

// ---- K2: softmax over S=4096 per batch row; input = sum of the 2 h-partials
__global__ __launch_bounds__(256) void k_softmax(
    const float* __restrict__ logits_part, float* __restrict__ out) {
  const int b = blockIdx.x;
  const int t = threadIdx.x;
  const int wid = t >> 6, lane = t & 63;
  const float* L0 = logits_part + b * 4096;
  const float* L1 = logits_part + 65536 + b * 4096;
  __shared__ float rmax[4], rsum[4];
  float lv[16];
  float m = -1e30f;
#pragma unroll
  for (int i = 0; i < 16; ++i) {
    lv[i] = L0[t + i * 256] + L1[t + i * 256];
    m = fmaxf(m, lv[i]);
  }
#pragma unroll
  for (int off = 32; off >= 1; off >>= 1) m = fmaxf(m, __shfl_xor(m, off));
  if (lane == 0) rmax[wid] = m;
  __syncthreads();
  m = fmaxf(fmaxf(rmax[0], rmax[1]), fmaxf(rmax[2], rmax[3]));
  float s = 0.f;
#pragma unroll
  for (int i = 0; i < 16; ++i) {
    lv[i] = __expf(lv[i] - m);
    s += lv[i];
  }
#pragma unroll
  for (int off = 32; off >= 1; off >>= 1) s += __shfl_xor(s, off);
  if (lane == 0) rsum[wid] = s;
  __syncthreads();
  s = rsum[0] + rsum[1] + rsum[2] + rsum[3];
  float inv = 1.0f / s;
#pragma unroll
  for (int i = 0; i < 16; ++i) out[b * 4096 + t + i * 256] = lv[i] * inv;
}

extern "C" void kernel_launch(void* const* d_in, const int* in_sizes, int n_in,
                              void* d_out, int out_size, void* d_ws, size_t ws_size,
                              hipStream_t stream) {
  const float* hidden = (const float*)d_in[0];   // [16,512]
  const float* enc    = (const float*)d_in[1];   // [16,4096,1024]
  const float* W      = (const float*)d_in[2];   // [512,1536]
  const float* bias   = (const float*)d_in[3];   // [512]
  const float* v      = (const float*)d_in[4];   // [512]
  float* out = (float*)d_out;                    // [16,4096]

  char* ws = (char*)d_ws;
  float* P = (float*)ws;                                       // 32 KB
  unsigned short* W2t = (unsigned short*)(ws + 32768);         // 1 MB
  float* logits_part = (float*)(ws + 32768 + 1048576);         // 2 x 256 KB

  k_prep_p<<<16, 256, 0, stream>>>(hidden, W, bias, P);
  k_prep_w<<<256, 256, 0, stream>>>(W, W2t);
  k_main<<<1024, 512, 0, stream>>>(enc, (const short*)W2t, P, v, logits_part);
  k_softmax<<<16, 256, 0, stream>>>(logits_part, out);
}